// Round 15
// baseline (2731.240 us; speedup 1.0000x reference)
//
#include <hip/hip_runtime.h>
#include <hip/hip_bf16.h>
#include <stdint.h>

// out[b,o] = sum_{k,i} hyp[b,k]*h[b,i]*W2[k,i*256+o] + sum_i h[b,i]*b2[i*256+o] + bias[o]
// GEMM A[4096 x 131328] * B[131328 x 256], A = diag(hyp_k)*H per k-group — all FP16,
// 16x16x32 MFMA. BARRIER-FREE K-loop (1x8 wave grid: each wave stages exactly the 4KB
// slice it reads) + register double-buffer of next tile's B-frags+scale (scaling stays
// inline in the MFMA cluster — R14's pre-scale spilled). 2-slot LDS ring (72KB LDS ->
// 2 blocks/CU = 4 waves/SIMD for cross-wave latency hiding), per-wave counted vmcnt,
// lgkmcnt(0) WAR-guard before each stage. 16 K-slabs x 32 mt = grid 512 (2 blocks/CU
// everywhere), slab==bid&15 keeps XCD affinity. One block-wide barrier total.
// ws: [0,8M) hypT fp32 [512][4096]; [9M,+2M) h f16; [12M,+67.2M) packed B tiles.

typedef _Float16 f16x8 __attribute__((ext_vector_type(8)));
typedef float    f32x4 __attribute__((ext_vector_type(4)));

#define KTILES     2052
#define TILE_BYTES 32768          // 64 k * 256 cols * 2B
#define HB_OFF     (9u*1024u*1024u)
#define BP_OFF     (12u*1024u*1024u)

// ---------------- out = bias ----------------
__global__ void k_init_out(const float* __restrict__ bias, float* __restrict__ out) {
    int idx = blockIdx.x * 256 + threadIdx.x;
    out[idx] = bias[idx & 255];
}

// ---------------- h fp32 -> f16 ----------------
__global__ void k_hcast(const float* __restrict__ h, _Float16* __restrict__ hb) {
    int i = (blockIdx.x * 256 + threadIdx.x) * 8;    // grid 512 x 256
    f32x4 a = *(const f32x4*)(h + i);
    f32x4 b = *(const f32x4*)(h + i + 4);
    f16x8 v;
    v[0] = (_Float16)a[0]; v[1] = (_Float16)a[1]; v[2] = (_Float16)a[2]; v[3] = (_Float16)a[3];
    v[4] = (_Float16)b[0]; v[5] = (_Float16)b[1]; v[6] = (_Float16)b[2]; v[7] = (_Float16)b[3];
    *(f16x8*)(hb + i) = v;
}

// ---------------- hypT[k][b] = relu(z@W1+b1)^T ----------------
__global__ void k_hypT(const float* __restrict__ z, const float* __restrict__ W1,
                       const float* __restrict__ b1, float* __restrict__ hypT) {
    int blk = blockIdx.x;
    int t   = threadIdx.x;                       // 512 threads; t == k
    __shared__ float zs[32][128];
    int b0 = blk * 32;
#pragma unroll
    for (int u = 0; u < 8; ++u) {
        int idx = u * 512 + t;
        zs[idx >> 7][idx & 127] = z[b0 * 128 + idx];
    }
    __syncthreads();
    float acc[32];
    float bk = b1[t];
#pragma unroll
    for (int b = 0; b < 32; ++b) acc[b] = bk;
    for (int c = 0; c < 128; ++c) {
        float w = W1[c * 512 + t];
#pragma unroll
        for (int b = 0; b < 32; ++b) acc[b] = fmaf(zs[b][c], w, acc[b]);
    }
    float* dst = hypT + (size_t)t * 4096 + b0;
#pragma unroll
    for (int v = 0; v < 8; ++v) {
        f32x4 o;
#pragma unroll
        for (int q = 0; q < 4; ++q) {
            float a = acc[v * 4 + q];
            o[q] = a > 0.f ? a : 0.f;
        }
        *(f32x4*)(dst + v * 4) = o;
    }
}

// ---------------- pack W2 (+b2) -> f16 transposed+swizzled tiles ----------------
// dst element (kk,o) at byte (o*128 + kk*2) ^ ((o&7)<<4); build in LDS, stream out 16B.
__global__ void k_pack(const float* __restrict__ W2, const float* __restrict__ b2,
                       _Float16* __restrict__ Bp) {
    __shared__ char tile[TILE_BYTES];
    int t   = blockIdx.x;
    int tid = threadIdx.x;        // 256
    long row0 = (long)t * 64;
    const float* src = (t < 2048) ? (W2 + row0 * 256) : (b2 + (row0 - 131072) * 256);
#pragma unroll
    for (int u = 0; u < 16; ++u) {
        int f = (u * 256 + tid) * 4;              // flat fp32 idx, coalesced
        f32x4 v = *(const f32x4*)(src + f);
        int kk = f >> 8;
        int o0 = f & 255;
#pragma unroll
        for (int j = 0; j < 4; ++j) {
            int o = o0 + j;
            int addr = (o * 128 + kk * 2) ^ ((o & 7) << 4);
            *(_Float16*)(tile + addr) = (_Float16)v[j];
        }
    }
    __syncthreads();
    char* dst = (char*)Bp + (size_t)t * TILE_BYTES;
#pragma unroll
    for (int v = 0; v < 8; ++v) {
        int off = (v * 256 + tid) * 16;           // coalesced 16B copy out
        *(f32x4*)(dst + off) = *(const f32x4*)(tile + off);
    }
}

// ---------------- main GEMM: BM=128, BN=256, 8 waves (1x8), 2-slot ring --------------
// grid 512 = 16 K-slabs x 32 mt; LDS = 2x32KB ring + 8KB shyp = 72KB -> 2 blocks/CU.
__global__ __launch_bounds__(512, 4) void k_gemm(
        const _Float16* __restrict__ hb, const float* __restrict__ hypT,
        const _Float16* __restrict__ Bp, float* __restrict__ out) {
    __shared__ char smem[73728];   // slots 0/1 at s*32768; shyp f16 at 65536

    const int tid  = threadIdx.x;
    const int lane = tid & 63;
    const int wid  = tid >> 6;                 // 8 waves; wave owns cols [wid*32,+32)
    const int l15  = lane & 15, lg = lane >> 4;

    const int bid = blockIdx.x;                // 512
    const int s   = bid & 15;                  // K-slab; XCD = s&7 (16 == 0 mod 8)
    const int mt  = bid >> 4;                  // 0..31
    const int k0  = s * 32;
    const int row_base = mt * 128;
    const int NT  = (s == 15) ? 132 : 128;     // slab 15 owns the 4 b2 tiles

    _Float16* shyp = (_Float16*)(smem + 65536);   // [32 kk][16 l15][8 mf] f16

    // ---- prologue: hyp slab (32 kk x 128 rows) -> LDS, lane-transposed ----
#pragma unroll
    for (int u = 0; u < 2; ++u) {
        int f  = (u * 512 + tid) * 4;          // 4096 floats
        int kk = f >> 7;
        int r  = f & 127;
        f32x4 v = *(const f32x4*)(hypT + (size_t)(k0 + kk) * 4096 + row_base + r);
#pragma unroll
        for (int q = 0; q < 4; ++q) {
            int rr = r + q;                    // rr = mf*16 + l15
            shyp[kk * 128 + (rr & 15) * 8 + (rr >> 4)] = (_Float16)v[q];
        }
    }

    auto tile_of = [&](int idx) {
        return (idx < 128) ? ((k0 + (idx & 31)) * 4 + (idx >> 5)) : (2048 + idx - 128);
    };
    // wave stages ITS OWN 4KB slice (cols [wid*32,+32)) of the 32KB tile
    auto stage = [&](int slot, int t) {
        const char* gsrc = (const char*)Bp + (size_t)t * TILE_BYTES + wid * 4096 + lane * 16;
        char* ldst = smem + slot * 32768 + wid * 4096;   // wave-uniform base, lane*16 implicit
#pragma unroll
        for (int q = 0; q < 4; ++q)
            __builtin_amdgcn_global_load_lds(
                (const __attribute__((address_space(1))) void*)(gsrc + q * 1024),
                (__attribute__((address_space(3))) void*)(ldst + q * 1024), 16, 0, 0);
    };

    stage(0, tile_of(0));
    stage(1, tile_of(1));
    __syncthreads();               // shyp visible; drains vmcnt (one-time)

    f32x4 acc[8][2];
#pragma unroll
    for (int i = 0; i < 8; ++i)
#pragma unroll
        for (int j = 0; j < 2; ++j)
#pragma unroll
            for (int q = 0; q < 4; ++q) acc[i][j][q] = 0.0f;

    f16x8 one8;
#pragma unroll
    for (int q = 0; q < 8; ++q) one8[q] = (_Float16)1.0f;

    // per-lane loop-invariant B-frag byte offsets within a slot
    int boff0[2], boff1[2];
#pragma unroll
    for (int nf = 0; nf < 2; ++nf) {
        int col = wid * 32 + nf * 16 + l15;
        int swz = (col & 7) << 4;
        boff0[nf] = (col * 128 + lg * 16) ^ swz;
        boff1[nf] = (col * 128 + 64 + lg * 16) ^ swz;
    }

    // register double-buffer sets: B-frags + scale (A scaled inline in MFMA cluster)
    f16x8 b0A[2], b1A[2], b0B[2], b1B[2];
    f16x8 scA, scB;
    f16x8 af[8][2];

    // ---- load af for G=0; read tile 0's frags + scale into set A ----
#pragma unroll
    for (int mf = 0; mf < 8; ++mf)
#pragma unroll
        for (int ks = 0; ks < 2; ++ks)
            af[mf][ks] = *(const f16x8*)(hb + (size_t)(row_base + mf * 16 + l15) * 256
                                         + ks * 32 + lg * 8);
    {
#pragma unroll
        for (int nf = 0; nf < 2; ++nf) {
            b0A[nf] = *(const f16x8*)(smem + boff0[nf]);
            b1A[nf] = *(const f16x8*)(smem + boff1[nf]);
        }
        scA = *(const f16x8*)(shyp + l15 * 8);
    }

// pipeline step: lgkm WAR-guard; stage idx+2 into slot idx&1; counted-wait idx+1; read
// idx+1 frags+scale into NXT set; MFMA cluster on CUR (scale inline, per-mf VALU
// overlaps prior mf's MFMA within the wave; cross-wave overlap via 4 waves/SIMD).
#define PIPE(B0C, B1C, SCC_, B0N, B1N, SCN_, IDX)                                             \
  {                                                                                           \
    const int _i = (IDX);                                                                     \
    if (_i + 2 < NT) {                                                                        \
      asm volatile("s_waitcnt lgkmcnt(0)" ::: "memory");  /* WAR: idx's reads done */         \
      stage(_i & 1, tile_of(_i + 2));                                                         \
    }                                                                                         \
    if (_i + 1 < NT) {                                                                        \
      if (_i + 2 < NT) asm volatile("s_waitcnt vmcnt(4)" ::: "memory");                       \
      else             asm volatile("s_waitcnt vmcnt(0)" ::: "memory");                       \
      const char* _sB = smem + ((_i + 1) & 1) * 32768;                                        \
      _Pragma("unroll")                                                                       \
      for (int nf = 0; nf < 2; ++nf) {                                                        \
        B0N[nf] = *(const f16x8*)(_sB + boff0[nf]);                                           \
        B1N[nf] = *(const f16x8*)(_sB + boff1[nf]);                                           \
      }                                                                                       \
      SCN_ = (_i + 1 < 128) ? *(const f16x8*)(shyp + ((_i + 1) & 31) * 128 + l15 * 8) : one8; \
    }                                                                                         \
    __builtin_amdgcn_s_setprio(1);                                                            \
    _Pragma("unroll")                                                                         \
    for (int mf = 0; mf < 8; ++mf) {                                                          \
      f16x8 _a0 = af[mf][0] * SCC_[mf];                                                       \
      f16x8 _a1 = af[mf][1] * SCC_[mf];                                                       \
      acc[mf][0] = __builtin_amdgcn_mfma_f32_16x16x32_f16(_a0, B0C[0], acc[mf][0], 0, 0, 0);  \
      acc[mf][1] = __builtin_amdgcn_mfma_f32_16x16x32_f16(_a0, B0C[1], acc[mf][1], 0, 0, 0);  \
      acc[mf][0] = __builtin_amdgcn_mfma_f32_16x16x32_f16(_a1, B1C[0], acc[mf][0], 0, 0, 0);  \
      acc[mf][1] = __builtin_amdgcn_mfma_f32_16x16x32_f16(_a1, B1C[1], acc[mf][1], 0, 0, 0);  \
    }                                                                                         \
    __builtin_amdgcn_s_setprio(0);                                                            \
  }

    for (int G = 0; G < 4; ++G) {
        if (G > 0) {
            // new i0-group: reload af (16 global 16B loads; covered by next vmcnt(4))
#pragma unroll
            for (int mf = 0; mf < 8; ++mf)
#pragma unroll
                for (int ks = 0; ks < 2; ++ks)
                    af[mf][ks] = *(const f16x8*)(hb + (size_t)(row_base + mf * 16 + l15) * 256
                                                 + G * 64 + ks * 32 + lg * 8);
        }
        for (int jj = 0; jj < 32; jj += 2) {
            const int idx = G * 32 + jj;
            PIPE(b0A, b1A, scA, b0B, b1B, scB, idx);
            PIPE(b0B, b1B, scB, b0A, b1A, scA, idx + 1);
        }
    }

    // ---- b2 tail (slab 15 only): tiles 128..131 (=2048..2051), scale 1 ----
    if (s == 15) {
        // entering: slot0 holds tile 128 (landed), tile 129 in flight to slot 1
        for (int g = 0; g < 4; ++g) {
            int idx = 128 + g;
            if (g == 1 || g == 2) asm volatile("s_waitcnt vmcnt(4)" ::: "memory");
            if (g == 3)           asm volatile("s_waitcnt vmcnt(0)" ::: "memory");
            const char* sB = smem + (idx & 1) * 32768;
            f16x8 t0[2], t1[2];
#pragma unroll
            for (int nf = 0; nf < 2; ++nf) {
                t0[nf] = *(const f16x8*)(sB + boff0[nf]);
                t1[nf] = *(const f16x8*)(sB + boff1[nf]);
            }
            f16x8 tf[8][2];
#pragma unroll
            for (int mf = 0; mf < 8; ++mf)
#pragma unroll
                for (int ks = 0; ks < 2; ++ks)
                    tf[mf][ks] = *(const f16x8*)(hb + (size_t)(row_base + mf * 16 + l15) * 256
                                                 + g * 64 + ks * 32 + lg * 8);
            if (g < 2) {   // stage 130 -> slot0 (g=0), 131 -> slot1 (g=1)
                asm volatile("s_waitcnt lgkmcnt(0)" ::: "memory");
                stage(idx & 1, tile_of(idx + 2));
            }
#pragma unroll
            for (int mf = 0; mf < 8; ++mf) {
                acc[mf][0] = __builtin_amdgcn_mfma_f32_16x16x32_f16(tf[mf][0], t0[0], acc[mf][0], 0, 0, 0);
                acc[mf][1] = __builtin_amdgcn_mfma_f32_16x16x32_f16(tf[mf][0], t0[1], acc[mf][1], 0, 0, 0);
                acc[mf][0] = __builtin_amdgcn_mfma_f32_16x16x32_f16(tf[mf][1], t1[0], acc[mf][0], 0, 0, 0);
                acc[mf][1] = __builtin_amdgcn_mfma_f32_16x16x32_f16(tf[mf][1], t1[1], acc[mf][1], 0, 0, 0);
            }
        }
    }

    // ---- epilogue: atomic split-K accumulate (out pre-initialized with bias) ----
#pragma unroll
    for (int mf = 0; mf < 8; ++mf)
#pragma unroll
        for (int nf = 0; nf < 2; ++nf) {
            int col = wid * 32 + nf * 16 + l15;
#pragma unroll
            for (int q = 0; q < 4; ++q) {
                int row = row_base + mf * 16 + lg * 4 + q;  // C/D: col=lane&15, row=(lane>>4)*4+q
                atomicAdd(&out[row * 256 + col], acc[mf][nf][q]);
            }
        }
}

extern "C" void kernel_launch(void* const* d_in, const int* in_sizes, int n_in,
                              void* d_out, int out_size, void* d_ws, size_t ws_size,
                              hipStream_t stream) {
    const float* h    = (const float*)d_in[0];  // [4096,256]
    const float* z    = (const float*)d_in[1];  // [4096,128]
    const float* W1   = (const float*)d_in[2];  // [128,512]
    const float* b1   = (const float*)d_in[3];  // [512]
    const float* W2   = (const float*)d_in[4];  // [512,65536]
    const float* b2   = (const float*)d_in[5];  // [65536]
    const float* bias = (const float*)d_in[6];  // [1,256]
    float* out = (float*)d_out;                 // [4096,256] fp32

    float*     hypT = (float*)d_ws;                          // 512*4096*4 = 8 MB
    _Float16*  hb   = (_Float16*)((char*)d_ws + HB_OFF);     // 2 MB f16 h
    _Float16*  Bp   = (_Float16*)((char*)d_ws + BP_OFF);     // 67.2 MB

    k_pack    <<<KTILES, 256, 0, stream>>>(W2, b2, Bp);
    k_hypT    <<<128,    512, 0, stream>>>(z, W1, b1, hypT);
    k_hcast   <<<512,    256, 0, stream>>>(h, hb);
    k_init_out<<<4096,   256, 0, stream>>>(bias, out);
    k_gemm    <<<512,    512, 0, stream>>>(hb, hypT, Bp, out);
}

// Round 16
// 339.683 us; speedup vs baseline: 8.0406x; 8.0406x over previous
//
#include <hip/hip_runtime.h>
#include <hip/hip_bf16.h>
#include <stdint.h>

// out[b,o] = sum_{k,i} hyp[b,k]*h[b,i]*W2[k,i*256+o] + sum_i h[b,i]*b2[i*256+o] + bias[o]
// GEMM A[4096 x 131328] * B[131328 x 256], A = diag(hyp_k)*H per k-group — all FP16,
// 16x16x32 MFMA. BARRIER-FREE K-loop (1x8 wave grid: each wave stages exactly the 4KB
// slice it reads) + register double-buffer of next tile's B-frags+scale (scaling inline
// in the MFMA cluster). 2-slot LDS ring (72KB -> 2 blocks/CU = 4 waves/SIMD), per-wave
// counted vmcnt, lgkmcnt(0) WAR-guard before each stage. 16 K-slabs x 32 mt = grid 512.
// NOTE: hipcc's 2nd __launch_bounds__ arg acts as min BLOCKS/CU: (512,4) capped VGPR at
// 64 and spilled (R15, 12.6GB traffic); (512,2) -> cap 128, body uses ~108, no spill.
// ws: [0,8M) hypT fp32 [512][4096]; [9M,+2M) h f16; [12M,+67.2M) packed B tiles.

typedef _Float16 f16x8 __attribute__((ext_vector_type(8)));
typedef float    f32x4 __attribute__((ext_vector_type(4)));

#define KTILES     2052
#define TILE_BYTES 32768          // 64 k * 256 cols * 2B
#define HB_OFF     (9u*1024u*1024u)
#define BP_OFF     (12u*1024u*1024u)

// ---------------- out = bias ----------------
__global__ void k_init_out(const float* __restrict__ bias, float* __restrict__ out) {
    int idx = blockIdx.x * 256 + threadIdx.x;
    out[idx] = bias[idx & 255];
}

// ---------------- h fp32 -> f16 ----------------
__global__ void k_hcast(const float* __restrict__ h, _Float16* __restrict__ hb) {
    int i = (blockIdx.x * 256 + threadIdx.x) * 8;    // grid 512 x 256
    f32x4 a = *(const f32x4*)(h + i);
    f32x4 b = *(const f32x4*)(h + i + 4);
    f16x8 v;
    v[0] = (_Float16)a[0]; v[1] = (_Float16)a[1]; v[2] = (_Float16)a[2]; v[3] = (_Float16)a[3];
    v[4] = (_Float16)b[0]; v[5] = (_Float16)b[1]; v[6] = (_Float16)b[2]; v[7] = (_Float16)b[3];
    *(f16x8*)(hb + i) = v;
}

// ---------------- hypT[k][b] = relu(z@W1+b1)^T ----------------
__global__ void k_hypT(const float* __restrict__ z, const float* __restrict__ W1,
                       const float* __restrict__ b1, float* __restrict__ hypT) {
    int blk = blockIdx.x;
    int t   = threadIdx.x;                       // 512 threads; t == k
    __shared__ float zs[32][128];
    int b0 = blk * 32;
#pragma unroll
    for (int u = 0; u < 8; ++u) {
        int idx = u * 512 + t;
        zs[idx >> 7][idx & 127] = z[b0 * 128 + idx];
    }
    __syncthreads();
    float acc[32];
    float bk = b1[t];
#pragma unroll
    for (int b = 0; b < 32; ++b) acc[b] = bk;
    for (int c = 0; c < 128; ++c) {
        float w = W1[c * 512 + t];
#pragma unroll
        for (int b = 0; b < 32; ++b) acc[b] = fmaf(zs[b][c], w, acc[b]);
    }
    float* dst = hypT + (size_t)t * 4096 + b0;
#pragma unroll
    for (int v = 0; v < 8; ++v) {
        f32x4 o;
#pragma unroll
        for (int q = 0; q < 4; ++q) {
            float a = acc[v * 4 + q];
            o[q] = a > 0.f ? a : 0.f;
        }
        *(f32x4*)(dst + v * 4) = o;
    }
}

// ---------------- pack W2 (+b2) -> f16 transposed+swizzled tiles ----------------
// dst element (kk,o) at byte (o*128 + kk*2) ^ ((o&7)<<4); build in LDS, stream out 16B.
__global__ void k_pack(const float* __restrict__ W2, const float* __restrict__ b2,
                       _Float16* __restrict__ Bp) {
    __shared__ char tile[TILE_BYTES];
    int t   = blockIdx.x;
    int tid = threadIdx.x;        // 256
    long row0 = (long)t * 64;
    const float* src = (t < 2048) ? (W2 + row0 * 256) : (b2 + (row0 - 131072) * 256);
#pragma unroll
    for (int u = 0; u < 16; ++u) {
        int f = (u * 256 + tid) * 4;              // flat fp32 idx, coalesced
        f32x4 v = *(const f32x4*)(src + f);
        int kk = f >> 8;
        int o0 = f & 255;
#pragma unroll
        for (int j = 0; j < 4; ++j) {
            int o = o0 + j;
            int addr = (o * 128 + kk * 2) ^ ((o & 7) << 4);
            *(_Float16*)(tile + addr) = (_Float16)v[j];
        }
    }
    __syncthreads();
    char* dst = (char*)Bp + (size_t)t * TILE_BYTES;
#pragma unroll
    for (int v = 0; v < 8; ++v) {
        int off = (v * 256 + tid) * 16;           // coalesced 16B copy out
        *(f32x4*)(dst + off) = *(const f32x4*)(tile + off);
    }
}

// ---------------- main GEMM: BM=128, BN=256, 8 waves (1x8), 2-slot ring --------------
// grid 512 = 16 K-slabs x 32 mt; LDS = 2x32KB ring + 8KB shyp = 72KB -> 2 blocks/CU.
__global__ __launch_bounds__(512, 2) void k_gemm(
        const _Float16* __restrict__ hb, const float* __restrict__ hypT,
        const _Float16* __restrict__ Bp, float* __restrict__ out) {
    __shared__ char smem[73728];   // slots 0/1 at s*32768; shyp f16 at 65536

    const int tid  = threadIdx.x;
    const int lane = tid & 63;
    const int wid  = tid >> 6;                 // 8 waves; wave owns cols [wid*32,+32)
    const int l15  = lane & 15, lg = lane >> 4;

    const int bid = blockIdx.x;                // 512
    const int s   = bid & 15;                  // K-slab; XCD = s&7 (16 == 0 mod 8)
    const int mt  = bid >> 4;                  // 0..31
    const int k0  = s * 32;
    const int row_base = mt * 128;
    const int NT  = (s == 15) ? 132 : 128;     // slab 15 owns the 4 b2 tiles

    _Float16* shyp = (_Float16*)(smem + 65536);   // [32 kk][16 l15][8 mf] f16

    // ---- prologue: hyp slab (32 kk x 128 rows) -> LDS, lane-transposed ----
#pragma unroll
    for (int u = 0; u < 2; ++u) {
        int f  = (u * 512 + tid) * 4;          // 4096 floats
        int kk = f >> 7;
        int r  = f & 127;
        f32x4 v = *(const f32x4*)(hypT + (size_t)(k0 + kk) * 4096 + row_base + r);
#pragma unroll
        for (int q = 0; q < 4; ++q) {
            int rr = r + q;                    // rr = mf*16 + l15
            shyp[kk * 128 + (rr & 15) * 8 + (rr >> 4)] = (_Float16)v[q];
        }
    }

    auto tile_of = [&](int idx) {
        return (idx < 128) ? ((k0 + (idx & 31)) * 4 + (idx >> 5)) : (2048 + idx - 128);
    };
    // wave stages ITS OWN 4KB slice (cols [wid*32,+32)) of the 32KB tile
    auto stage = [&](int slot, int t) {
        const char* gsrc = (const char*)Bp + (size_t)t * TILE_BYTES + wid * 4096 + lane * 16;
        char* ldst = smem + slot * 32768 + wid * 4096;   // wave-uniform base, lane*16 implicit
#pragma unroll
        for (int q = 0; q < 4; ++q)
            __builtin_amdgcn_global_load_lds(
                (const __attribute__((address_space(1))) void*)(gsrc + q * 1024),
                (__attribute__((address_space(3))) void*)(ldst + q * 1024), 16, 0, 0);
    };

    stage(0, tile_of(0));
    stage(1, tile_of(1));
    __syncthreads();               // shyp visible; drains vmcnt (one-time)

    f32x4 acc[8][2];
#pragma unroll
    for (int i = 0; i < 8; ++i)
#pragma unroll
        for (int j = 0; j < 2; ++j)
#pragma unroll
            for (int q = 0; q < 4; ++q) acc[i][j][q] = 0.0f;

    f16x8 one8;
#pragma unroll
    for (int q = 0; q < 8; ++q) one8[q] = (_Float16)1.0f;

    // per-lane loop-invariant B-frag byte offsets within a slot
    int boff0[2], boff1[2];
#pragma unroll
    for (int nf = 0; nf < 2; ++nf) {
        int col = wid * 32 + nf * 16 + l15;
        int swz = (col & 7) << 4;
        boff0[nf] = (col * 128 + lg * 16) ^ swz;
        boff1[nf] = (col * 128 + 64 + lg * 16) ^ swz;
    }

    // register double-buffer sets: B-frags + scale (A scaled inline in MFMA cluster)
    f16x8 b0A[2], b1A[2], b0B[2], b1B[2];
    f16x8 scA, scB;
    f16x8 af[8][2];

    // ---- load af for G=0; read tile 0's frags + scale into set A ----
#pragma unroll
    for (int mf = 0; mf < 8; ++mf)
#pragma unroll
        for (int ks = 0; ks < 2; ++ks)
            af[mf][ks] = *(const f16x8*)(hb + (size_t)(row_base + mf * 16 + l15) * 256
                                         + ks * 32 + lg * 8);
    {
#pragma unroll
        for (int nf = 0; nf < 2; ++nf) {
            b0A[nf] = *(const f16x8*)(smem + boff0[nf]);
            b1A[nf] = *(const f16x8*)(smem + boff1[nf]);
        }
        scA = *(const f16x8*)(shyp + l15 * 8);
    }

// pipeline step: lgkm WAR-guard; stage idx+2 into slot idx&1; counted-wait idx+1; read
// idx+1 frags+scale into NXT set; MFMA cluster on CUR (scale inline; cross-wave overlap
// via 4 waves/SIMD, barrier-free private pipelines).
#define PIPE(B0C, B1C, SCC_, B0N, B1N, SCN_, IDX)                                             \
  {                                                                                           \
    const int _i = (IDX);                                                                     \
    if (_i + 2 < NT) {                                                                        \
      asm volatile("s_waitcnt lgkmcnt(0)" ::: "memory");  /* WAR: idx's reads done */         \
      stage(_i & 1, tile_of(_i + 2));                                                         \
    }                                                                                         \
    if (_i + 1 < NT) {                                                                        \
      if (_i + 2 < NT) asm volatile("s_waitcnt vmcnt(4)" ::: "memory");                       \
      else             asm volatile("s_waitcnt vmcnt(0)" ::: "memory");                       \
      const char* _sB = smem + ((_i + 1) & 1) * 32768;                                        \
      _Pragma("unroll")                                                                       \
      for (int nf = 0; nf < 2; ++nf) {                                                        \
        B0N[nf] = *(const f16x8*)(_sB + boff0[nf]);                                           \
        B1N[nf] = *(const f16x8*)(_sB + boff1[nf]);                                           \
      }                                                                                       \
      SCN_ = (_i + 1 < 128) ? *(const f16x8*)(shyp + ((_i + 1) & 31) * 128 + l15 * 8) : one8; \
    }                                                                                         \
    __builtin_amdgcn_s_setprio(1);                                                            \
    _Pragma("unroll")                                                                         \
    for (int mf = 0; mf < 8; ++mf) {                                                          \
      f16x8 _a0 = af[mf][0] * SCC_[mf];                                                       \
      f16x8 _a1 = af[mf][1] * SCC_[mf];                                                       \
      acc[mf][0] = __builtin_amdgcn_mfma_f32_16x16x32_f16(_a0, B0C[0], acc[mf][0], 0, 0, 0);  \
      acc[mf][1] = __builtin_amdgcn_mfma_f32_16x16x32_f16(_a0, B0C[1], acc[mf][1], 0, 0, 0);  \
      acc[mf][0] = __builtin_amdgcn_mfma_f32_16x16x32_f16(_a1, B1C[0], acc[mf][0], 0, 0, 0);  \
      acc[mf][1] = __builtin_amdgcn_mfma_f32_16x16x32_f16(_a1, B1C[1], acc[mf][1], 0, 0, 0);  \
    }                                                                                         \
    __builtin_amdgcn_s_setprio(0);                                                            \
  }

    for (int G = 0; G < 4; ++G) {
        if (G > 0) {
            // new i0-group: reload af (16 global 16B loads; covered by next vmcnt(4))
#pragma unroll
            for (int mf = 0; mf < 8; ++mf)
#pragma unroll
                for (int ks = 0; ks < 2; ++ks)
                    af[mf][ks] = *(const f16x8*)(hb + (size_t)(row_base + mf * 16 + l15) * 256
                                                 + G * 64 + ks * 32 + lg * 8);
        }
        for (int jj = 0; jj < 32; jj += 2) {
            const int idx = G * 32 + jj;
            PIPE(b0A, b1A, scA, b0B, b1B, scB, idx);
            PIPE(b0B, b1B, scB, b0A, b1A, scA, idx + 1);
        }
    }

    // ---- b2 tail (slab 15 only): tiles 128..131 (=2048..2051), scale 1 ----
    if (s == 15) {
        // entering: slot0 holds tile 128 (landed), tile 129 in flight to slot 1
        for (int g = 0; g < 4; ++g) {
            int idx = 128 + g;
            if (g == 1 || g == 2) asm volatile("s_waitcnt vmcnt(4)" ::: "memory");
            if (g == 3)           asm volatile("s_waitcnt vmcnt(0)" ::: "memory");
            const char* sB = smem + (idx & 1) * 32768;
            f16x8 t0[2], t1[2];
#pragma unroll
            for (int nf = 0; nf < 2; ++nf) {
                t0[nf] = *(const f16x8*)(sB + boff0[nf]);
                t1[nf] = *(const f16x8*)(sB + boff1[nf]);
            }
            f16x8 tf[8][2];
#pragma unroll
            for (int mf = 0; mf < 8; ++mf)
#pragma unroll
                for (int ks = 0; ks < 2; ++ks)
                    tf[mf][ks] = *(const f16x8*)(hb + (size_t)(row_base + mf * 16 + l15) * 256
                                                 + g * 64 + ks * 32 + lg * 8);
            if (g < 2) {   // stage 130 -> slot0 (g=0), 131 -> slot1 (g=1)
                asm volatile("s_waitcnt lgkmcnt(0)" ::: "memory");
                stage(idx & 1, tile_of(idx + 2));
            }
#pragma unroll
            for (int mf = 0; mf < 8; ++mf) {
                acc[mf][0] = __builtin_amdgcn_mfma_f32_16x16x32_f16(tf[mf][0], t0[0], acc[mf][0], 0, 0, 0);
                acc[mf][1] = __builtin_amdgcn_mfma_f32_16x16x32_f16(tf[mf][0], t0[1], acc[mf][1], 0, 0, 0);
                acc[mf][0] = __builtin_amdgcn_mfma_f32_16x16x32_f16(tf[mf][1], t1[0], acc[mf][0], 0, 0, 0);
                acc[mf][1] = __builtin_amdgcn_mfma_f32_16x16x32_f16(tf[mf][1], t1[1], acc[mf][1], 0, 0, 0);
            }
        }
    }

    // ---- epilogue: atomic split-K accumulate (out pre-initialized with bias) ----
#pragma unroll
    for (int mf = 0; mf < 8; ++mf)
#pragma unroll
        for (int nf = 0; nf < 2; ++nf) {
            int col = wid * 32 + nf * 16 + l15;
#pragma unroll
            for (int q = 0; q < 4; ++q) {
                int row = row_base + mf * 16 + lg * 4 + q;  // C/D: col=lane&15, row=(lane>>4)*4+q
                atomicAdd(&out[row * 256 + col], acc[mf][nf][q]);
            }
        }
}

extern "C" void kernel_launch(void* const* d_in, const int* in_sizes, int n_in,
                              void* d_out, int out_size, void* d_ws, size_t ws_size,
                              hipStream_t stream) {
    const float* h    = (const float*)d_in[0];  // [4096,256]
    const float* z    = (const float*)d_in[1];  // [4096,128]
    const float* W1   = (const float*)d_in[2];  // [128,512]
    const float* b1   = (const float*)d_in[3];  // [512]
    const float* W2   = (const float*)d_in[4];  // [512,65536]
    const float* b2   = (const float*)d_in[5];  // [65536]
    const float* bias = (const float*)d_in[6];  // [1,256]
    float* out = (float*)d_out;                 // [4096,256] fp32

    float*     hypT = (float*)d_ws;                          // 512*4096*4 = 8 MB
    _Float16*  hb   = (_Float16*)((char*)d_ws + HB_OFF);     // 2 MB f16 h
    _Float16*  Bp   = (_Float16*)((char*)d_ws + BP_OFF);     // 67.2 MB

    k_pack    <<<KTILES, 256, 0, stream>>>(W2, b2, Bp);
    k_hypT    <<<128,    512, 0, stream>>>(z, W1, b1, hypT);
    k_hcast   <<<512,    256, 0, stream>>>(h, hb);
    k_init_out<<<4096,   256, 0, stream>>>(bias, out);
    k_gemm    <<<512,    512, 0, stream>>>(hb, hypT, Bp, out);
}

// Round 17
// 302.884 us; speedup vs baseline: 9.0174x; 1.1215x over previous
//
#include <hip/hip_runtime.h>
#include <hip/hip_bf16.h>
#include <stdint.h>

// out[b,o] = sum_{k,i} hyp[b,k]*h[b,i]*W2[k,i*256+o] + sum_i h[b,i]*b2[i*256+o] + bias[o]
// GEMM A[4096 x 131328] * B[131328 x 256], A = diag(hyp_k)*H per k-group — all FP16,
// 16x16x32 MFMA. R10 base (best: 234.7us): BARRIER-FREE K-loop, 1x8 wave grid (each wave
// stages exactly the 4KB slice it reads), 4-slot LDS ring depth-3, per-wave counted vmcnt,
// register double-buffer of next tile's B-frags+scales.
// NEW: (1) ANTIPHASE wave groups — SIMD k hosts waves k and k+4; group B (wid>=4) runs
// MFMA(mf0-3) / loads / MFMA(mf4-7) so the CU-shared MFMA pipe is fed while group A loads
// (R10 showed MfmaUtil+VALUBusy = 104% -> zero overlap, phase-aligned waves).
// (2) dup-u32 scales: shyp32 holds f16 pairs duplicated; scale8 = 4 v_pk_mul, no splat.
// ws: [0,8M) hypT fp32 [512][4096]; [9M,+2M) h f16; [12M,+67.2M) packed B tiles.

typedef _Float16 f16x8 __attribute__((ext_vector_type(8)));
typedef _Float16 f16x2 __attribute__((ext_vector_type(2)));
typedef float    f32x4 __attribute__((ext_vector_type(4)));
typedef uint32_t u32x4 __attribute__((ext_vector_type(4)));

#define KTILES     2052
#define TILE_BYTES 32768          // 64 k * 256 cols * 2B
#define HB_OFF     (9u*1024u*1024u)
#define BP_OFF     (12u*1024u*1024u)

// ---------------- out = bias ----------------
__global__ void k_init_out(const float* __restrict__ bias, float* __restrict__ out) {
    int idx = blockIdx.x * 256 + threadIdx.x;
    out[idx] = bias[idx & 255];
}

// ---------------- h fp32 -> f16 ----------------
__global__ void k_hcast(const float* __restrict__ h, _Float16* __restrict__ hb) {
    int i = (blockIdx.x * 256 + threadIdx.x) * 8;    // grid 512 x 256
    f32x4 a = *(const f32x4*)(h + i);
    f32x4 b = *(const f32x4*)(h + i + 4);
    f16x8 v;
    v[0] = (_Float16)a[0]; v[1] = (_Float16)a[1]; v[2] = (_Float16)a[2]; v[3] = (_Float16)a[3];
    v[4] = (_Float16)b[0]; v[5] = (_Float16)b[1]; v[6] = (_Float16)b[2]; v[7] = (_Float16)b[3];
    *(f16x8*)(hb + i) = v;
}

// ---------------- hypT[k][b] = relu(z@W1+b1)^T ----------------
__global__ void k_hypT(const float* __restrict__ z, const float* __restrict__ W1,
                       const float* __restrict__ b1, float* __restrict__ hypT) {
    int blk = blockIdx.x;
    int t   = threadIdx.x;                       // 512 threads; t == k
    __shared__ float zs[32][128];
    int b0 = blk * 32;
#pragma unroll
    for (int u = 0; u < 8; ++u) {
        int idx = u * 512 + t;
        zs[idx >> 7][idx & 127] = z[b0 * 128 + idx];
    }
    __syncthreads();
    float acc[32];
    float bk = b1[t];
#pragma unroll
    for (int b = 0; b < 32; ++b) acc[b] = bk;
    for (int c = 0; c < 128; ++c) {
        float w = W1[c * 512 + t];
#pragma unroll
        for (int b = 0; b < 32; ++b) acc[b] = fmaf(zs[b][c], w, acc[b]);
    }
    float* dst = hypT + (size_t)t * 4096 + b0;
#pragma unroll
    for (int v = 0; v < 8; ++v) {
        f32x4 o;
#pragma unroll
        for (int q = 0; q < 4; ++q) {
            float a = acc[v * 4 + q];
            o[q] = a > 0.f ? a : 0.f;
        }
        *(f32x4*)(dst + v * 4) = o;
    }
}

// ---------------- pack W2 (+b2) -> f16 transposed+swizzled tiles ----------------
// dst element (kk,o) at byte (o*128 + kk*2) ^ ((o&7)<<4); build in LDS, stream out 16B.
__global__ void k_pack(const float* __restrict__ W2, const float* __restrict__ b2,
                       _Float16* __restrict__ Bp) {
    __shared__ char tile[TILE_BYTES];
    int t   = blockIdx.x;
    int tid = threadIdx.x;        // 256
    long row0 = (long)t * 64;
    const float* src = (t < 2048) ? (W2 + row0 * 256) : (b2 + (row0 - 131072) * 256);
#pragma unroll
    for (int u = 0; u < 16; ++u) {
        int f = (u * 256 + tid) * 4;              // flat fp32 idx, coalesced
        f32x4 v = *(const f32x4*)(src + f);
        int kk = f >> 8;
        int o0 = f & 255;
#pragma unroll
        for (int j = 0; j < 4; ++j) {
            int o = o0 + j;
            int addr = (o * 128 + kk * 2) ^ ((o & 7) << 4);
            *(_Float16*)(tile + addr) = (_Float16)v[j];
        }
    }
    __syncthreads();
    char* dst = (char*)Bp + (size_t)t * TILE_BYTES;
#pragma unroll
    for (int v = 0; v < 8; ++v) {
        int off = (v * 256 + tid) * 16;           // coalesced 16B copy out
        *(f32x4*)(dst + off) = *(const f32x4*)(tile + off);
    }
}

// scaled = a * dup(s): exactly 4 v_pk_mul_f16, no extract/splat
static __device__ __forceinline__ f16x8 scale8(f16x8 a, uint32_t s) {
    u32x4 ua = __builtin_bit_cast(u32x4, a);
    f16x2 sv = __builtin_bit_cast(f16x2, s);
    u32x4 r;
#pragma unroll
    for (int q = 0; q < 4; ++q) {
        f16x2 aq = __builtin_bit_cast(f16x2, (uint32_t)ua[q]);
        f16x2 rq = aq * sv;
        r[q] = __builtin_bit_cast(uint32_t, rq);
    }
    return __builtin_bit_cast(f16x8, r);
}

// ---------------- main GEMM: BM=128, BN=256, 8 waves (1x8), antiphase groups ---------
// grid 256 = 8 K-slabs (==XCD) x 32 mt; LDS = 4x32KB ring + 32KB dup-scales = 160KB.
__global__ __launch_bounds__(512, 2) void k_gemm(
        const _Float16* __restrict__ hb, const float* __restrict__ hypT,
        const _Float16* __restrict__ Bp, float* __restrict__ out) {
    __shared__ char smem[163840];   // slots 0..3 at s*32768; dup-scales u32[8192] at 131072

    const int tid  = threadIdx.x;
    const int lane = tid & 63;
    const int wid  = tid >> 6;                 // 8 waves; wave owns cols [wid*32,+32)
    const int l15  = lane & 15, lg = lane >> 4;
    const bool grpB = ((wid >> 2) & 1) != 0;   // SIMD k hosts waves k (grpA) and k+4 (grpB)

    const int bid = blockIdx.x;                // 256
    const int s   = bid & 7;                   // K-slab == XCD (round-robin dispatch)
    const int mt  = bid >> 3;                  // 0..31
    const int k0  = s * 64;
    const int row_base = mt * 128;
    const int NT  = (s == 7) ? 260 : 256;      // slab 7 owns the 4 b2 tiles

    uint32_t* shyp32 = (uint32_t*)(smem + 131072);   // [64 kk][16 l15][8 mf] dup'd f16

    // ---- prologue: hyp slab -> LDS as DUPLICATED f16 pairs, lane-transposed ----
#pragma unroll
    for (int u = 0; u < 4; ++u) {
        int f  = (u * 512 + tid) * 4;          // 8192 floats
        int kk = f >> 7;
        int r  = f & 127;
        f32x4 v = *(const f32x4*)(hypT + (size_t)(k0 + kk) * 4096 + row_base + r);
#pragma unroll
        for (int q = 0; q < 4; ++q) {
            int rr = r + q;                    // rr = mf*16 + l15
            _Float16 hf = (_Float16)v[q];
            uint32_t d  = (uint32_t)__builtin_bit_cast(uint16_t, hf) * 0x10001u;
            shyp32[kk * 128 + (rr & 15) * 8 + (rr >> 4)] = d;
        }
    }

    auto tile_of = [&](int idx) {
        return (idx < 256) ? ((k0 + (idx & 63)) * 4 + (idx >> 6)) : (2048 + idx - 256);
    };
    // wave stages ITS OWN 4KB slice (cols [wid*32,+32)) of the 32KB tile
    auto stage = [&](int slot, int t) {
        const char* gsrc = (const char*)Bp + (size_t)t * TILE_BYTES + wid * 4096 + lane * 16;
        char* ldst = smem + slot * 32768 + wid * 4096;   // wave-uniform base, lane*16 implicit
#pragma unroll
        for (int q = 0; q < 4; ++q)
            __builtin_amdgcn_global_load_lds(
                (const __attribute__((address_space(1))) void*)(gsrc + q * 1024),
                (__attribute__((address_space(3))) void*)(ldst + q * 1024), 16, 0, 0);
    };

    stage(0, tile_of(0));
    stage(1, tile_of(1));
    stage(2, tile_of(2));
    __syncthreads();               // dup-scales visible; drains vmcnt (one-time)

    f32x4 acc[8][2];
#pragma unroll
    for (int i = 0; i < 8; ++i)
#pragma unroll
        for (int j = 0; j < 2; ++j)
#pragma unroll
            for (int q = 0; q < 4; ++q) acc[i][j][q] = 0.0f;

    const u32x4 oneD = {0x3C003C00u, 0x3C003C00u, 0x3C003C00u, 0x3C003C00u};

    // per-lane loop-invariant B-frag byte offsets within a slot
    int boff0[2], boff1[2];
#pragma unroll
    for (int nf = 0; nf < 2; ++nf) {
        int col = wid * 32 + nf * 16 + l15;
        int swz = (col & 7) << 4;
        boff0[nf] = (col * 128 + lg * 16) ^ swz;
        boff1[nf] = (col * 128 + 64 + lg * 16) ^ swz;
    }
    const int soff = l15 * 8;      // u32 index of this lane's 8 dup'd scales

    // register double-buffer sets: B-frags + dup-scales (A scaled inline, 4 pk_mul/frag)
    f16x8 b0A[2], b1A[2], b0B[2], b1B[2];
    u32x4 sA0, sA1, sB0, sB1;      // mf 0..3 / mf 4..7
    f16x8 af[8][2];

    // ---- load af for G=0; read tile 0's frags + scales into set A ----
#pragma unroll
    for (int mf = 0; mf < 8; ++mf)
#pragma unroll
        for (int ks = 0; ks < 2; ++ks)
            af[mf][ks] = *(const f16x8*)(hb + (size_t)(row_base + mf * 16 + l15) * 256
                                         + ks * 32 + lg * 8);
    {
#pragma unroll
        for (int nf = 0; nf < 2; ++nf) {
            b0A[nf] = *(const f16x8*)(smem + boff0[nf]);
            b1A[nf] = *(const f16x8*)(smem + boff1[nf]);
        }
        sA0 = *(const u32x4*)(shyp32 + soff);
        sA1 = *(const u32x4*)(shyp32 + soff + 4);
    }

// loads segment: stage idx+3; counted wait; read idx+1's B-frags + dup-scales into NXT
#define LOADS(B0N, B1N, SN0, SN1, IDX)                                                        \
  {                                                                                           \
    const int _i = (IDX);                                                                     \
    if (_i + 3 < NT) stage((_i + 3) & 3, tile_of(_i + 3));                                    \
    if (_i + 1 < NT) {                                                                        \
      int _stg  = (_i + 3 < NT) ? _i + 3 : NT - 1;                                            \
      int _pend = _stg - (_i + 1);                                                            \
      if (_pend >= 2)      asm volatile("s_waitcnt vmcnt(8)" ::: "memory");                   \
      else if (_pend == 1) asm volatile("s_waitcnt vmcnt(4)" ::: "memory");                   \
      else                 asm volatile("s_waitcnt vmcnt(0)" ::: "memory");                   \
      const char* _sB = smem + ((_i + 1) & 3) * 32768;                                        \
      _Pragma("unroll")                                                                       \
      for (int nf = 0; nf < 2; ++nf) {                                                        \
        B0N[nf] = *(const f16x8*)(_sB + boff0[nf]);                                           \
        B1N[nf] = *(const f16x8*)(_sB + boff1[nf]);                                           \
      }                                                                                       \
      if (_i + 1 < 256) {                                                                     \
        const uint32_t* _sp = shyp32 + ((_i + 1) & 63) * 128 + soff;                          \
        SN0 = *(const u32x4*)_sp;                                                             \
        SN1 = *(const u32x4*)(_sp + 4);                                                       \
      } else { SN0 = oneD; SN1 = oneD; }                                                      \
    }                                                                                         \
  }

// half MFMA cluster: mf MF0..MF0+3 on CUR set (16 MFMAs + 8 scale8)
#define MF4(MF0, SD, B0C, B1C)                                                                \
  __builtin_amdgcn_s_setprio(1);                                                             \
  _Pragma("unroll")                                                                           \
  for (int mf = MF0; mf < MF0 + 4; ++mf) {                                                    \
    f16x8 _a0 = scale8(af[mf][0], SD[mf - MF0]);                                              \
    f16x8 _a1 = scale8(af[mf][1], SD[mf - MF0]);                                              \
    acc[mf][0] = __builtin_amdgcn_mfma_f32_16x16x32_f16(_a0, B0C[0], acc[mf][0], 0, 0, 0);    \
    acc[mf][1] = __builtin_amdgcn_mfma_f32_16x16x32_f16(_a0, B0C[1], acc[mf][1], 0, 0, 0);    \
    acc[mf][0] = __builtin_amdgcn_mfma_f32_16x16x32_f16(_a1, B1C[0], acc[mf][0], 0, 0, 0);    \
    acc[mf][1] = __builtin_amdgcn_mfma_f32_16x16x32_f16(_a1, B1C[1], acc[mf][1], 0, 0, 0);    \
  }                                                                                           \
  __builtin_amdgcn_s_setprio(0);

// group A: loads first, then full cluster. group B: half cluster / loads / half cluster.
#define PIPE_A(B0C, B1C, S0C, S1C, B0N, B1N, S0N, S1N, IDX)                                   \
  { LOADS(B0N, B1N, S0N, S1N, IDX); MF4(0, S0C, B0C, B1C); MF4(4, S1C, B0C, B1C); }

#define PIPE_B(B0C, B1C, S0C, S1C, B0N, B1N, S0N, S1N, IDX)                                   \
  { MF4(0, S0C, B0C, B1C);                                                                    \
    __builtin_amdgcn_sched_barrier(0);                                                        \
    LOADS(B0N, B1N, S0N, S1N, IDX);                                                           \
    __builtin_amdgcn_sched_barrier(0);                                                        \
    MF4(4, S1C, B0C, B1C); }

    for (int G = 0; G < 4; ++G) {
        if (G > 0) {
            // new i0-group: reload af (16 global 16B loads)
#pragma unroll
            for (int mf = 0; mf < 8; ++mf)
#pragma unroll
                for (int ks = 0; ks < 2; ++ks)
                    af[mf][ks] = *(const f16x8*)(hb + (size_t)(row_base + mf * 16 + l15) * 256
                                                 + G * 64 + ks * 32 + lg * 8);
        }
        if (!grpB) {
            for (int jj = 0; jj < 64; jj += 2) {
                const int idx = G * 64 + jj;
                PIPE_A(b0A, b1A, sA0, sA1, b0B, b1B, sB0, sB1, idx);
                PIPE_A(b0B, b1B, sB0, sB1, b0A, b1A, sA0, sA1, idx + 1);
            }
        } else {
            for (int jj = 0; jj < 64; jj += 2) {
                const int idx = G * 64 + jj;
                PIPE_B(b0A, b1A, sA0, sA1, b0B, b1B, sB0, sB1, idx);
                PIPE_B(b0B, b1B, sB0, sB1, b0A, b1A, sA0, sA1, idx + 1);
            }
        }
    }

    // ---- b2 tail (slab 7 only): tiles 256..259, scale 1 (unscaled af) ----
    if (s == 7) {
        for (int g = 0; g < 4; ++g) {
            int idx = 256 + g;
            if (idx + 3 < 260) stage((idx + 3) & 3, tile_of(idx + 3));
            asm volatile("s_waitcnt vmcnt(0)" ::: "memory");
            f16x8 tf[8][2];
#pragma unroll
            for (int mf = 0; mf < 8; ++mf)
#pragma unroll
                for (int ks = 0; ks < 2; ++ks)
                    tf[mf][ks] = *(const f16x8*)(hb + (size_t)(row_base + mf * 16 + l15) * 256
                                                 + g * 64 + ks * 32 + lg * 8);
            const char* sB = smem + (idx & 3) * 32768;
            f16x8 t0[2], t1[2];
#pragma unroll
            for (int nf = 0; nf < 2; ++nf) {
                t0[nf] = *(const f16x8*)(sB + boff0[nf]);
                t1[nf] = *(const f16x8*)(sB + boff1[nf]);
            }
#pragma unroll
            for (int mf = 0; mf < 8; ++mf) {
                acc[mf][0] = __builtin_amdgcn_mfma_f32_16x16x32_f16(tf[mf][0], t0[0], acc[mf][0], 0, 0, 0);
                acc[mf][1] = __builtin_amdgcn_mfma_f32_16x16x32_f16(tf[mf][0], t0[1], acc[mf][1], 0, 0, 0);
                acc[mf][0] = __builtin_amdgcn_mfma_f32_16x16x32_f16(tf[mf][1], t1[0], acc[mf][0], 0, 0, 0);
                acc[mf][1] = __builtin_amdgcn_mfma_f32_16x16x32_f16(tf[mf][1], t1[1], acc[mf][1], 0, 0, 0);
            }
        }
    }

    // ---- epilogue: atomic split-K accumulate (out pre-initialized with bias) ----
#pragma unroll
    for (int mf = 0; mf < 8; ++mf)
#pragma unroll
        for (int nf = 0; nf < 2; ++nf) {
            int col = wid * 32 + nf * 16 + l15;
#pragma unroll
            for (int q = 0; q < 4; ++q) {
                int row = row_base + mf * 16 + lg * 4 + q;  // C/D: col=lane&15, row=(lane>>4)*4+q
                atomicAdd(&out[row * 256 + col], acc[mf][nf][q]);
            }
        }
}

extern "C" void kernel_launch(void* const* d_in, const int* in_sizes, int n_in,
                              void* d_out, int out_size, void* d_ws, size_t ws_size,
                              hipStream_t stream) {
    const float* h    = (const float*)d_in[0];  // [4096,256]
    const float* z    = (const float*)d_in[1];  // [4096,128]
    const float* W1   = (const float*)d_in[2];  // [128,512]
    const float* b1   = (const float*)d_in[3];  // [512]
    const float* W2   = (const float*)d_in[4];  // [512,65536]
    const float* b2   = (const float*)d_in[5];  // [65536]
    const float* bias = (const float*)d_in[6];  // [1,256]
    float* out = (float*)d_out;                 // [4096,256] fp32

    float*     hypT = (float*)d_ws;                          // 512*4096*4 = 8 MB
    _Float16*  hb   = (_Float16*)((char*)d_ws + HB_OFF);     // 2 MB f16 h
    _Float16*  Bp   = (_Float16*)((char*)d_ws + BP_OFF);     // 67.2 MB

    k_pack    <<<KTILES, 256, 0, stream>>>(W2, b2, Bp);
    k_hypT    <<<128,    512, 0, stream>>>(z, W1, b1, hypT);
    k_hcast   <<<512,    256, 0, stream>>>(h, hb);
    k_init_out<<<4096,   256, 0, stream>>>(bias, out);
    k_gemm    <<<256,    512, 0, stream>>>(hb, hypT, Bp, out);
}